// Round 1
// baseline (457.857 us; speedup 1.0000x reference)
//
#include <hip/hip_runtime.h>

// Problem constants (from reference)
#define PP 4
#define QQ 16
#define NQ 128
#define HH 256
#define P5 1024   // PP^5

// ---------------------------------------------------------------------------
// Block-wide sum over 256 threads (4 waves). All threads return the total.
// ---------------------------------------------------------------------------
__device__ __forceinline__ float block_sum256(float v, float* red, int t) {
#pragma unroll
  for (int o = 32; o > 0; o >>= 1) v += __shfl_down(v, o, 64);
  if ((t & 63) == 0) red[t >> 6] = v;
  __syncthreads();
  float r = red[0] + red[1] + red[2] + red[3];
  __syncthreads();
  return r;
}

// ---------------------------------------------------------------------------
// Prep kernel (1 block, 256 threads):
//   1. per-quad scalars A_i = sum_r y_r*qx_r, B_i = sum_r y_r  (y = exp(-qx^2*eq))
//   2. s_i[j] = Wq_i[j]*A_i + bq_i[j]*B_i          (5 x 64)
//   3. rhs[idx] = sum_x s0[b,x] s1[d,x] s2[f,x] s3[m,x] s4[v,x]   (1024)
//   4. w2r[h] = sum_j Wx2[h,j]*rhs[j]  ;  b2r = sum_j bx2[j]*rhs[j]
//   5. pack ws[h*8 + {0,1,2,3,4}] = {Wx1[0][h], Wx1[1][h], Wx1[2][h], bx1[h], w2r[h]}
//      ws[2048] = b2r
// ---------------------------------------------------------------------------
__global__ __launch_bounds__(256) void prep_kernel(
    const float* __restrict__ eq,
    const float* __restrict__ q0, const float* __restrict__ q1,
    const float* __restrict__ q2, const float* __restrict__ q3,
    const float* __restrict__ q4,
    const float* __restrict__ Wx1, const float* __restrict__ bx1,
    const float* __restrict__ Wx2, const float* __restrict__ bx2,
    const float* __restrict__ Wq0, const float* __restrict__ bq0,
    const float* __restrict__ Wq1, const float* __restrict__ bq1,
    const float* __restrict__ Wq2, const float* __restrict__ bq2,
    const float* __restrict__ Wq3, const float* __restrict__ bq3,
    const float* __restrict__ Wq4, const float* __restrict__ bq4,
    float* __restrict__ ws) {
  __shared__ float red[4];
  __shared__ float sS[5][64];
  __shared__ float sRhs[P5];

  const int t = threadIdx.x;
  const float eqv = eq[0];

  const float* qs[5]  = {q0, q1, q2, q3, q4};
  const float* Wqs[5] = {Wq0, Wq1, Wq2, Wq3, Wq4};
  const float* bqs[5] = {bq0, bq1, bq2, bq3, bq4};

  float A[5], B[5];
#pragma unroll
  for (int i = 0; i < 5; ++i) {
    float a = 0.f, b = 0.f;
    if (t < NQ) {
      float x = qs[i][t];
      float y = expf(-x * x * eqv);
      a = y * x;
      b = y;
    }
    A[i] = block_sum256(a, red, t);
    B[i] = block_sum256(b, red, t);
  }

  // s_i[j]
  for (int k = t; k < 5 * 64; k += 256) {
    int i = k >> 6, j = k & 63;
    sS[i][j] = Wqs[i][j] * A[i] + bqs[i][j] * B[i];
  }
  __syncthreads();

  // rhs
  for (int idx = t; idx < P5; idx += 256) {
    int b = (idx >> 8) & 3, d = (idx >> 6) & 3, f = (idx >> 4) & 3,
        m = (idx >> 2) & 3, v = idx & 3;
    float s = 0.f;
#pragma unroll
    for (int x = 0; x < QQ; ++x)
      s += sS[0][b * QQ + x] * sS[1][d * QQ + x] * sS[2][f * QQ + x] *
           sS[3][m * QQ + x] * sS[4][v * QQ + x];
    sRhs[idx] = s;
  }
  __syncthreads();

  // w2r: one wave per h (coalesced reads of Wx2 row), 4 waves round-robin
  const int wv = t >> 6, ln = t & 63;
  for (int h = wv; h < HH; h += 4) {
    float p = 0.f;
    for (int j = ln; j < P5; j += 64) p = fmaf(Wx2[h * P5 + j], sRhs[j], p);
#pragma unroll
    for (int o = 32; o > 0; o >>= 1) p += __shfl_down(p, o, 64);
    if (ln == 0) ws[h * 8 + 4] = p;
  }

  // pack Wx1 / bx1 (Wx1 layout: [3][256] row-major)
  if (t < HH) {
    ws[t * 8 + 0] = Wx1[t];
    ws[t * 8 + 1] = Wx1[HH + t];
    ws[t * 8 + 2] = Wx1[2 * HH + t];
    ws[t * 8 + 3] = bx1[t];
  }

  // b2r
  float pb = 0.f;
  for (int j = t; j < P5; j += 256) pb = fmaf(bx2[j], sRhs[j], pb);
  pb = block_sum256(pb, red, t);
  if (t == 0) ws[HH * 8] = pb;
}

// ---------------------------------------------------------------------------
// Main kernel: out[i] = sum_h tanh(b_h + x.W_h) * w2r[h] + b2r
// 2 threads per row (h-range split 128/128), combined with shfl_xor.
// Weight reads are wave-uniform -> expect s_load scalarization.
// ---------------------------------------------------------------------------
__global__ __launch_bounds__(256) void main_kernel(
    const float* __restrict__ input, const float* __restrict__ pk,
    float* __restrict__ out, int n) {
  const int gid = blockIdx.x * 256 + threadIdx.x;
  const int row = gid >> 1;
  if (row >= n) return;
  const int half = gid & 1;

  const float x0 = input[row * 3 + 0];
  const float x1 = input[row * 3 + 1];
  const float x2 = input[row * 3 + 2];

  const float* __restrict__ p = pk + half * (HH / 2) * 8;
  float acc = 0.f;
#pragma unroll 4
  for (int h = 0; h < HH / 2; ++h) {
    const float w0 = p[h * 8 + 0];
    const float w1 = p[h * 8 + 1];
    const float w2 = p[h * 8 + 2];
    const float b  = p[h * 8 + 3];
    const float wr = p[h * 8 + 4];
    float a = fmaf(x2, w2, fmaf(x1, w1, fmaf(x0, w0, b)));
    // tanh(a) = 1 - 2/(e^{2a}+1); saturates correctly for |a| large
    float ex = __expf(2.0f * a);
    float tnh = fmaf(-2.0f, __builtin_amdgcn_rcpf(ex + 1.0f), 1.0f);
    acc = fmaf(tnh, wr, acc);
  }
  acc += __shfl_xor(acc, 1, 64);
  if (half == 0) out[row] = acc + pk[HH * 8];
}

// ---------------------------------------------------------------------------
extern "C" void kernel_launch(void* const* d_in, const int* in_sizes, int n_in,
                              void* d_out, int out_size, void* d_ws,
                              size_t ws_size, hipStream_t stream) {
  const float* input = (const float*)d_in[0];
  const float* eq    = (const float*)d_in[1];
  const float* q0    = (const float*)d_in[2];
  const float* q1    = (const float*)d_in[3];
  const float* q2    = (const float*)d_in[4];
  const float* q3    = (const float*)d_in[5];
  const float* q4    = (const float*)d_in[6];
  const float* Wx1   = (const float*)d_in[7];
  const float* bx1   = (const float*)d_in[8];
  const float* Wx2   = (const float*)d_in[9];
  const float* bx2   = (const float*)d_in[10];
  const float* Wq0   = (const float*)d_in[11];
  const float* bq0   = (const float*)d_in[12];
  const float* Wq1   = (const float*)d_in[13];
  const float* bq1   = (const float*)d_in[14];
  const float* Wq2   = (const float*)d_in[15];
  const float* bq2   = (const float*)d_in[16];
  const float* Wq3   = (const float*)d_in[17];
  const float* bq3   = (const float*)d_in[18];
  const float* Wq4   = (const float*)d_in[19];
  const float* bq4   = (const float*)d_in[20];

  float* ws  = (float*)d_ws;
  float* out = (float*)d_out;
  const int n = in_sizes[0] / 3;  // N = 100000

  hipLaunchKernelGGL(prep_kernel, dim3(1), dim3(256), 0, stream,
                     eq, q0, q1, q2, q3, q4, Wx1, bx1, Wx2, bx2,
                     Wq0, bq0, Wq1, bq1, Wq2, bq2, Wq3, bq3, Wq4, bq4, ws);

  const int total  = 2 * n;
  const int blocks = (total + 255) / 256;
  hipLaunchKernelGGL(main_kernel, dim3(blocks), dim3(256), 0, stream,
                     input, ws, out, n);
}

// Round 2
// 118.869 us; speedup vs baseline: 3.8518x; 3.8518x over previous
//
#include <hip/hip_runtime.h>

// Problem constants (from reference)
#define PP 4
#define QQ 16
#define NQ 128
#define HH 256
#define P5 1024   // PP^5

// ---------------------------------------------------------------------------
// Block-wide sum over 256 threads (4 waves). All threads return the total.
// ---------------------------------------------------------------------------
__device__ __forceinline__ float block_sum256(float v, float* red, int t) {
#pragma unroll
  for (int o = 32; o > 0; o >>= 1) v += __shfl_down(v, o, 64);
  if ((t & 63) == 0) red[t >> 6] = v;
  __syncthreads();
  float r = red[0] + red[1] + red[2] + red[3];
  __syncthreads();
  return r;
}

// ---------------------------------------------------------------------------
// Prep kernel — grid of HH=256 blocks, 256 threads each.
// EVERY block redundantly computes the tiny rhs vector (a few KB of reads,
// ~80K FLOP) in LDS, then block b computes its single w2r[b] = dot(Wx2[b,:],
// rhs) with a coalesced 4KB row read — this spreads the 1MB Wx2 stream over
// 256 CUs (the single-block version was HBM-latency-bound at 400 µs).
// Block 0 additionally packs {Wx1, bx1} and computes b2r.
// Output layout in ws:
//   ws[h*8 + {0,1,2,3,4}] = {Wx1[0][h], Wx1[1][h], Wx1[2][h], bx1[h], w2r[h]}
//   ws[2048] = b2r
// ---------------------------------------------------------------------------
__global__ __launch_bounds__(256) void prep_kernel(
    const float* __restrict__ eq,
    const float* __restrict__ q0, const float* __restrict__ q1,
    const float* __restrict__ q2, const float* __restrict__ q3,
    const float* __restrict__ q4,
    const float* __restrict__ Wx1, const float* __restrict__ bx1,
    const float* __restrict__ Wx2, const float* __restrict__ bx2,
    const float* __restrict__ Wq0, const float* __restrict__ bq0,
    const float* __restrict__ Wq1, const float* __restrict__ bq1,
    const float* __restrict__ Wq2, const float* __restrict__ bq2,
    const float* __restrict__ Wq3, const float* __restrict__ bq3,
    const float* __restrict__ Wq4, const float* __restrict__ bq4,
    float* __restrict__ ws) {
  __shared__ float red[4];
  __shared__ float sS[5][64];
  __shared__ float sRhs[P5];

  const int t = threadIdx.x;
  const int hb = blockIdx.x;  // the h this block owns
  const float eqv = eq[0];

  const float* qs[5]  = {q0, q1, q2, q3, q4};
  const float* Wqs[5] = {Wq0, Wq1, Wq2, Wq3, Wq4};
  const float* bqs[5] = {bq0, bq1, bq2, bq3, bq4};

  // A_i = sum_r y*qx, B_i = sum_r y, with y = exp(-qx^2 * eq)
  float A[5], B[5];
#pragma unroll
  for (int i = 0; i < 5; ++i) {
    float a = 0.f, b = 0.f;
    if (t < NQ) {
      float x = qs[i][t];
      float y = expf(-x * x * eqv);
      a = y * x;
      b = y;
    }
    A[i] = block_sum256(a, red, t);
    B[i] = block_sum256(b, red, t);
  }

  // s_i[j] = Wq_i[j]*A_i + bq_i[j]*B_i
  for (int k = t; k < 5 * 64; k += 256) {
    int i = k >> 6, j = k & 63;
    sS[i][j] = Wqs[i][j] * A[i] + bqs[i][j] * B[i];
  }
  __syncthreads();

  // rhs[idx] = sum_x s0[b,x] s1[d,x] s2[f,x] s3[m,x] s4[v,x]
  for (int idx = t; idx < P5; idx += 256) {
    int b = (idx >> 8) & 3, d = (idx >> 6) & 3, f = (idx >> 4) & 3,
        m = (idx >> 2) & 3, v = idx & 3;
    float s = 0.f;
#pragma unroll
    for (int x = 0; x < QQ; ++x)
      s += sS[0][b * QQ + x] * sS[1][d * QQ + x] * sS[2][f * QQ + x] *
           sS[3][m * QQ + x] * sS[4][v * QQ + x];
    sRhs[idx] = s;
  }
  __syncthreads();

  // w2r[hb] = dot(Wx2[hb,:], rhs): 4 elements per thread, block reduce.
  const float* wrow = Wx2 + hb * P5;
  float p = 0.f;
#pragma unroll
  for (int k = 0; k < 4; ++k)
    p = fmaf(wrow[t + 256 * k], sRhs[t + 256 * k], p);
  p = block_sum256(p, red, t);
  if (t == 0) ws[hb * 8 + 4] = p;

  if (hb == 0) {
    // pack Wx1 ([3][256] row-major) and bx1
    if (t < HH) {
      ws[t * 8 + 0] = Wx1[t];
      ws[t * 8 + 1] = Wx1[HH + t];
      ws[t * 8 + 2] = Wx1[2 * HH + t];
      ws[t * 8 + 3] = bx1[t];
    }
    // b2r = dot(bx2, rhs)
    float pb = 0.f;
    for (int j = t; j < P5; j += 256) pb = fmaf(bx2[j], sRhs[j], pb);
    pb = block_sum256(pb, red, t);
    if (t == 0) ws[HH * 8] = pb;
  }
}

// ---------------------------------------------------------------------------
// Main kernel: out[i] = sum_h tanh(b_h + x_i . W_h) * w2r[h] + b2r
// Block = 256 threads = 4 waves covering 64 rows (row = blockBase + lane).
// Wave w handles h in [w*64, w*64+64) — the weight-table addresses are
// IDENTICAL across the 64 lanes of a wave (uniform), so they scalarize /
// broadcast out of L1 instead of burning vector-memory bandwidth.
// Partials combined across the 4 waves through LDS.
// ---------------------------------------------------------------------------
__global__ __launch_bounds__(256) void main_kernel(
    const float* __restrict__ input, const float* __restrict__ pk,
    float* __restrict__ out, int n) {
  __shared__ float sacc[4][64];
  const int lane = threadIdx.x & 63;
  const int wv   = threadIdx.x >> 6;
  const int row  = blockIdx.x * 64 + lane;
  const bool valid = row < n;

  float x0 = 0.f, x1 = 0.f, x2 = 0.f;
  if (valid) {
    x0 = input[row * 3 + 0];
    x1 = input[row * 3 + 1];
    x2 = input[row * 3 + 2];
  }

  const float* __restrict__ p = pk + wv * 64 * 8;  // wave-uniform base
  float acc = 0.f;
#pragma unroll 8
  for (int h = 0; h < 64; ++h) {
    const float w0 = p[h * 8 + 0];
    const float w1 = p[h * 8 + 1];
    const float w2 = p[h * 8 + 2];
    const float b  = p[h * 8 + 3];
    const float wr = p[h * 8 + 4];
    float a = fmaf(x2, w2, fmaf(x1, w1, fmaf(x0, w0, b)));
    // tanh(a) = 1 - 2/(e^{2a}+1); saturates correctly for |a| large
    float ex = __expf(2.0f * a);
    float tnh = fmaf(-2.0f, __builtin_amdgcn_rcpf(ex + 1.0f), 1.0f);
    acc = fmaf(tnh, wr, acc);
  }
  sacc[wv][lane] = acc;
  __syncthreads();

  if (wv == 0 && valid) {
    float r = sacc[0][lane] + sacc[1][lane] + sacc[2][lane] + sacc[3][lane];
    out[row] = r + pk[HH * 8];
  }
}

// ---------------------------------------------------------------------------
extern "C" void kernel_launch(void* const* d_in, const int* in_sizes, int n_in,
                              void* d_out, int out_size, void* d_ws,
                              size_t ws_size, hipStream_t stream) {
  const float* input = (const float*)d_in[0];
  const float* eq    = (const float*)d_in[1];
  const float* q0    = (const float*)d_in[2];
  const float* q1    = (const float*)d_in[3];
  const float* q2    = (const float*)d_in[4];
  const float* q3    = (const float*)d_in[5];
  const float* q4    = (const float*)d_in[6];
  const float* Wx1   = (const float*)d_in[7];
  const float* bx1   = (const float*)d_in[8];
  const float* Wx2   = (const float*)d_in[9];
  const float* bx2   = (const float*)d_in[10];
  const float* Wq0   = (const float*)d_in[11];
  const float* bq0   = (const float*)d_in[12];
  const float* Wq1   = (const float*)d_in[13];
  const float* bq1   = (const float*)d_in[14];
  const float* Wq2   = (const float*)d_in[15];
  const float* bq2   = (const float*)d_in[16];
  const float* Wq3   = (const float*)d_in[17];
  const float* bq3   = (const float*)d_in[18];
  const float* Wq4   = (const float*)d_in[19];
  const float* bq4   = (const float*)d_in[20];

  float* ws  = (float*)d_ws;
  float* out = (float*)d_out;
  const int n = in_sizes[0] / 3;  // N = 100000

  hipLaunchKernelGGL(prep_kernel, dim3(HH), dim3(256), 0, stream,
                     eq, q0, q1, q2, q3, q4, Wx1, bx1, Wx2, bx2,
                     Wq0, bq0, Wq1, bq1, Wq2, bq2, Wq3, bq3, Wq4, bq4, ws);

  const int blocks = (n + 63) / 64;  // 64 rows per block
  hipLaunchKernelGGL(main_kernel, dim3(blocks), dim3(256), 0, stream,
                     input, ws, out, n);
}